// Round 4
// baseline (1124.485 us; speedup 1.0000x reference)
//
#include <hip/hip_runtime.h>
#include <hip/hip_bf16.h>

#define NN 50000
#define NE 800000

typedef unsigned short u16;
typedef unsigned int u32;

__device__ __forceinline__ float bf2f(u16 u) {
    u32 x = ((u32)u) << 16;
    return __uint_as_float(x);
}
__device__ __forceinline__ u16 f2bf(float f) {
    u32 x = __float_as_uint(f);
    u32 r = (x + 0x7fffu + ((x >> 16) & 1u)) >> 16;  // round-nearest-even
    return (u16)r;
}
__device__ __forceinline__ u32 pack2(float a, float b) {
    return (u32)f2bf(a) | ((u32)f2bf(b) << 16);
}
__device__ __forceinline__ void unpack8(uint4 u, float* o) {
    o[0] = bf2f((u16)(u.x & 0xffff)); o[1] = bf2f((u16)(u.x >> 16));
    o[2] = bf2f((u16)(u.y & 0xffff)); o[3] = bf2f((u16)(u.y >> 16));
    o[4] = bf2f((u16)(u.z & 0xffff)); o[5] = bf2f((u16)(u.z >> 16));
    o[6] = bf2f((u16)(u.w & 0xffff)); o[7] = bf2f((u16)(u.w >> 16));
}
__device__ __forceinline__ float ldf(const void* p, size_t idx, int mode) {
    return mode ? bf2f(((const u16*)p)[idx]) : ((const float*)p)[idx];
}
__device__ __forceinline__ void ld8(const void* p, size_t idx, int mode, float* o) {
    if (mode) {
        uint4 u = *(const uint4*)((const u16*)p + idx);
        unpack8(u, o);
    } else {
        const float* f = (const float*)p + idx;
        float4 x = *(const float4*)f;
        float4 y = *(const float4*)(f + 4);
        o[0] = x.x; o[1] = x.y; o[2] = x.z; o[3] = x.w;
        o[4] = y.x; o[5] = y.y; o[6] = y.z; o[7] = y.w;
    }
}

// ---------------- diagnostics ----------------
__global__ void k_tracer(float* out, float v) {
    if (threadIdx.x == 0 && blockIdx.x == 0) out[0] = v;
}

// ---------------- dtype detect (0 = f32 inputs, 1 = bf16 inputs) ----------------
__global__ void k_detect(const u16* __restrict__ fvs, int* __restrict__ mode) {
    __shared__ int cnt[256];
    int t = threadIdx.x;
    int bad = 0;
    for (int i = 0; i < 16; i++) {
        u16 u = fvs[(size_t)(t * 16 + i) * 2];
        int e = (u >> 7) & 0xff;
        if (e == 255 || e >= 134 || e <= 100) bad++;
    }
    cnt[t] = bad;
    __syncthreads();
    for (int d = 128; d; d >>= 1) {
        if (t < d) cnt[t] += cnt[t + d];
        __syncthreads();
    }
    if (t == 0) *mode = (cnt[0] > 2048) ? 0 : 1;
}

// ---------------- CSR build ----------------
__global__ void k_hist(const int* __restrict__ dst, int* __restrict__ cnt, int E) {
    int e = blockIdx.x * blockDim.x + threadIdx.x;
    if (e < E) atomicAdd(&cnt[dst[e]], 1);
}

__global__ void k_scan(const int* __restrict__ cnt, int* __restrict__ off, int N) {
    __shared__ int sums[1024];
    int t = threadIdx.x;
    int chunk = (N + 1023) >> 10;
    int b = t * chunk;
    int s = 0;
    for (int i = 0; i < chunk; i++) { int idx = b + i; if (idx < N) s += cnt[idx]; }
    sums[t] = s;
    __syncthreads();
    for (int d = 1; d < 1024; d <<= 1) {
        int v = (t >= d) ? sums[t - d] : 0;
        __syncthreads();
        sums[t] += v;
        __syncthreads();
    }
    int run = (t == 0) ? 0 : sums[t - 1];
    for (int i = 0; i < chunk; i++) {
        int idx = b + i;
        if (idx < N) { off[idx] = run; run += cnt[idx]; }
    }
    if (t == 1023) off[N] = sums[1023];
}

__global__ void k_fill(const int* __restrict__ src, const int* __restrict__ dst,
                       const int* __restrict__ off, int* __restrict__ cnt2,
                       int* __restrict__ ssrc, int E) {
    int e = blockIdx.x * blockDim.x + threadIdx.x;
    if (e < E) {
        int d = dst[e];
        int p = off[d] + atomicAdd(&cnt2[d], 1);
        ssrc[p] = src[e];
    }
}

// ---------------- init: hp = bf16(pos) ----------------
__global__ void k_init(const void* __restrict__ pos, u16* __restrict__ hp,
                       const int* __restrict__ dmode, int n64) {
    int i = blockIdx.x * blockDim.x + threadIdx.x;
    if (i >= n64) return;
    int mode = *dmode;
    hp[i] = mode ? ((const u16*)pos)[i] : f2bf(((const float*)pos)[i]);
}

// ---------------- hp (bf16) -> f32 ----------------
__global__ void k_cvt(const u16* __restrict__ in, float* __restrict__ out, int n) {
    int i = blockIdx.x * blockDim.x + threadIdx.x;
    if (i < n) out[i] = bf2f(in[i]);
}

// ---------------- GEMM: C1[N,BM](f32), C2[N,BM](bf16) = [A1|A2][N,K] x B ----------------
// A1 and C2 may alias (in-place); each block reads/writes only its own 64 rows.
template <int BM, bool HASB2>
__launch_bounds__(256)
__global__ void k_gemm(const void* A1, const u16* __restrict__ A2,
                       const void* __restrict__ B1, const void* __restrict__ B2,
                       float* __restrict__ C1, u16* C2,
                       int N, int K, int s1, const int* __restrict__ dmode,
                       int a1_input) {
    constexpr int TN = BM / 16;  // 8 or 4
    __shared__ float As[64][32];
    __shared__ float Bs1[32][BM];
    __shared__ float Bs2[HASB2 ? 32 : 1][HASB2 ? BM : 1];

    int mode = *dmode;
    int amode = a1_input ? mode : 1;
    int tid = threadIdx.x;
    int tx = tid & 15, ty = tid >> 4;
    int r0 = blockIdx.x * 64;
    int arow = tid >> 2;
    int acs = (tid & 3) * 8;

    float acc1[4][TN], acc2[4][TN];
#pragma unroll
    for (int r = 0; r < 4; r++)
#pragma unroll
        for (int c = 0; c < TN; c++) { acc1[r][c] = 0.f; acc2[r][c] = 0.f; }

    for (int k0 = 0; k0 < K; k0 += 32) {
        {
            int gr = r0 + arow;
            float av[8];
#pragma unroll
            for (int i = 0; i < 8; i++) av[i] = 0.f;
            if (gr < N) {
                if (k0 >= 128) {
                    uint4 u = *(const uint4*)&A2[(size_t)gr * 64 + (k0 - 128) + acs];
                    unpack8(u, av);
                } else if (amode) {
                    uint4 u = *(const uint4*)((const u16*)A1 + (size_t)gr * s1 + k0 + acs);
                    unpack8(u, av);
                } else {
                    const float* Af = (const float*)A1 + (size_t)gr * s1 + k0 + acs;
                    float4 x = *(const float4*)Af;
                    float4 y = *(const float4*)(Af + 4);
                    av[0] = x.x; av[1] = x.y; av[2] = x.z; av[3] = x.w;
                    av[4] = y.x; av[5] = y.y; av[6] = y.z; av[7] = y.w;
                }
            }
            *(float4*)&As[arow][acs] = make_float4(av[0], av[1], av[2], av[3]);
            *(float4*)&As[arow][acs + 4] = make_float4(av[4], av[5], av[6], av[7]);
        }
#pragma unroll
        for (int t = 0; t < BM / 64; t++) {
            int f8 = tid + t * 256;
            int row = f8 / (BM / 8);
            int col = (f8 - row * (BM / 8)) * 8;
            ld8(B1, (size_t)(k0 + row) * BM + col, mode, &Bs1[row][col]);
            if constexpr (HASB2) ld8(B2, (size_t)(k0 + row) * BM + col, mode, &Bs2[row][col]);
        }
        __syncthreads();
#pragma unroll
        for (int kk = 0; kk < 32; kk++) {
            float a[4];
#pragma unroll
            for (int r = 0; r < 4; r++) a[r] = As[ty * 4 + r][kk];
            float b1[TN];
#pragma unroll
            for (int c = 0; c < TN; c++) b1[c] = Bs1[kk][tx * TN + c];
#pragma unroll
            for (int r = 0; r < 4; r++)
#pragma unroll
                for (int c = 0; c < TN; c++) acc1[r][c] = fmaf(a[r], b1[c], acc1[r][c]);
            if constexpr (HASB2) {
                float b2[TN];
#pragma unroll
                for (int c = 0; c < TN; c++) b2[c] = Bs2[kk][tx * TN + c];
#pragma unroll
                for (int r = 0; r < 4; r++)
#pragma unroll
                    for (int c = 0; c < TN; c++) acc2[r][c] = fmaf(a[r], b2[c], acc2[r][c]);
            }
        }
        __syncthreads();
    }
#pragma unroll
    for (int r = 0; r < 4; r++) {
        int gr = r0 + ty * 4 + r;
        if (gr >= N) continue;
        if constexpr (TN == 8) {
            *(float4*)&C1[(size_t)gr * BM + tx * TN] =
                make_float4(acc1[r][0], acc1[r][1], acc1[r][2], acc1[r][3]);
            *(float4*)&C1[(size_t)gr * BM + tx * TN + 4] =
                make_float4(acc1[r][4], acc1[r][5], acc1[r][6], acc1[r][7]);
            if constexpr (HASB2) {
                uint4 o2 = make_uint4(pack2(acc2[r][0], acc2[r][1]), pack2(acc2[r][2], acc2[r][3]),
                                      pack2(acc2[r][4], acc2[r][5]), pack2(acc2[r][6], acc2[r][7]));
                *(uint4*)&C2[(size_t)gr * BM + tx * TN] = o2;
            }
        } else {
            *(float4*)&C1[(size_t)gr * BM + tx * TN] =
                make_float4(acc1[r][0], acc1[r][1], acc1[r][2], acc1[r][3]);
        }
    }
}

// ---------------- el/er reductions ----------------
__global__ void k_eler_gat(const float* __restrict__ h, const void* __restrict__ al,
                           const void* __restrict__ ar, float* __restrict__ el,
                           float* __restrict__ er, const int* __restrict__ dmode, int N) {
    int node = blockIdx.x * (blockDim.x >> 6) + (threadIdx.x >> 6);
    int lane = threadIdx.x & 63;
    if (node >= N) return;
    int mode = *dmode;
    float h0 = h[(size_t)node * 128 + lane];
    float h1 = h[(size_t)node * 128 + 64 + lane];
    float e0 = h0 * ldf(al, lane, mode), e1 = h1 * ldf(al, 64 + lane, mode);
    float r0 = h0 * ldf(ar, lane, mode), r1 = h1 * ldf(ar, 64 + lane, mode);
#pragma unroll
    for (int o = 32; o; o >>= 1) {
        e0 += __shfl_xor(e0, o, 64); e1 += __shfl_xor(e1, o, 64);
        r0 += __shfl_xor(r0, o, 64); r1 += __shfl_xor(r1, o, 64);
    }
    if (lane == 0) {
        el[2 * node] = e0; el[2 * node + 1] = e1;
        er[2 * node] = r0; er[2 * node + 1] = r1;
    }
}

__global__ void k_eler_pg(const float* __restrict__ h, const void* __restrict__ al,
                          const void* __restrict__ ar, float* __restrict__ el,
                          float* __restrict__ er, const int* __restrict__ dmode, int N) {
    int node = blockIdx.x * (blockDim.x >> 6) + (threadIdx.x >> 6);
    int lane = threadIdx.x & 63;
    if (node >= N) return;
    int mode = *dmode;
    float hv = h[(size_t)node * 64 + lane];
    float e = hv * ldf(al, lane, mode);
    float r = hv * ldf(ar, lane, mode);
#pragma unroll
    for (int o = 16; o; o >>= 1) {
        e += __shfl_xor(e, o, 64);
        r += __shfl_xor(r, o, 64);
    }
    if ((lane & 31) == 0) {
        int head = lane >> 5;
        el[2 * node + head] = e;
        er[2 * node + head] = r;
    }
}

// ---------------- edge aggregation (online softmax, one wave per dst) ----------------
// res and outf may alias (same node row only).
__global__ void k_edge_gat(const int* __restrict__ off, const int* __restrict__ ssrc,
                           const float* __restrict__ h, const float* __restrict__ el,
                           const float* __restrict__ er, const u16* res,
                           u16* outf, float* outs,
                           int N, int final_mean) {
    int node = blockIdx.x * (blockDim.x >> 6) + (threadIdx.x >> 6);
    int lane = threadIdx.x & 63;
    if (node >= N) return;
    int beg = off[node], end = off[node + 1];
    float er0 = er[2 * node], er1 = er[2 * node + 1];
    float m0 = -1e30f, l0 = 0.f, O0 = 0.f;
    float m1 = -1e30f, l1 = 0.f, O1 = 0.f;
    for (int j = beg; j < end; j++) {
        int s = ssrc[j];
        float x0 = el[2 * s] + er0;     x0 = x0 > 0.f ? x0 : 0.2f * x0;
        float x1 = el[2 * s + 1] + er1; x1 = x1 > 0.f ? x1 : 0.2f * x1;
        float nm0 = fmaxf(m0, x0), nm1 = fmaxf(m1, x1);
        float s0 = __expf(m0 - nm0), s1 = __expf(m1 - nm1);
        float p0 = __expf(x0 - nm0), p1 = __expf(x1 - nm1);
        float hv0 = h[(size_t)s * 128 + lane];
        float hv1 = h[(size_t)s * 128 + 64 + lane];
        l0 = l0 * s0 + p0; l1 = l1 * s1 + p1;
        O0 = O0 * s0 + hv0 * p0; O1 = O1 * s1 + hv1 * p1;
        m0 = nm0; m1 = nm1;
    }
    float o0 = (end > beg) ? O0 / l0 : 0.f;
    float o1 = (end > beg) ? O1 / l1 : 0.f;
    float a0 = o0 + bf2f(res[(size_t)node * 128 + lane]);
    float a1 = o1 + bf2f(res[(size_t)node * 128 + 64 + lane]);
    a0 = a0 > 0.f ? a0 : (__expf(a0) - 1.f);  // elu
    a1 = a1 > 0.f ? a1 : (__expf(a1) - 1.f);
    if (final_mean) {
        outs[(size_t)node * 64 + lane] = 0.5f * (a0 + a1);
    } else {
        outf[(size_t)node * 128 + lane] = f2bf(a0);
        outf[(size_t)node * 128 + 64 + lane] = f2bf(a1);
    }
}

__global__ void k_edge_pg(const int* __restrict__ off, const int* __restrict__ ssrc,
                          const float* __restrict__ h, const float* __restrict__ el,
                          const float* __restrict__ er, u16* hp, int N) {
    int node = blockIdx.x * (blockDim.x >> 6) + (threadIdx.x >> 6);
    int lane = threadIdx.x & 63;
    if (node >= N) return;
    int head = lane >> 5;
    int beg = off[node], end = off[node + 1];
    float ert = er[2 * node + head];
    float m = -1e30f, l = 0.f, O = 0.f;
    for (int j = beg; j < end; j++) {
        int s = ssrc[j];
        float x = el[2 * s + head] + ert;
        x = x > 0.f ? x : 0.2f * x;
        float nm = fmaxf(m, x);
        float sc = __expf(m - nm), p = __expf(x - nm);
        float hv = h[(size_t)s * 64 + lane];
        l = l * sc + p;
        O = O * sc + hv * p;
        m = nm;
    }
    float o = (end > beg) ? O / l : 0.f;
    float a = tanhf(o + bf2f(hp[(size_t)node * 64 + lane]));
    hp[(size_t)node * 64 + lane] = f2bf(a);
}

// ---------------- launch ----------------
extern "C" void kernel_launch(void* const* d_in, const int* in_sizes, int n_in,
                              void* d_out, int out_size, void* d_ws, size_t ws_size,
                              hipStream_t stream) {
    const int N = NN, E = NE;
    const void* fvs = d_in[0];
    const void* pos = d_in[1];
    const int* src = (const int*)d_in[2];
    const int* dst = (const int*)d_in[3];
    const void* gW[3]  = {d_in[4],  d_in[8],  d_in[12]};
    const void* gal[3] = {d_in[5],  d_in[9],  d_in[13]};
    const void* gar[3] = {d_in[6],  d_in[10], d_in[14]};
    const void* grW[3] = {d_in[7],  d_in[11], d_in[15]};
    const void* pW[2]  = {d_in[16], d_in[19]};
    const void* pal[2] = {d_in[17], d_in[20]};
    const void* par[2] = {d_in[18], d_in[21]};

    // ---- workspace layout (wrap-safe: never OOB even if ws_size too small) ----
    auto al256 = [](size_t b) { return (b + 255) & ~(size_t)255; };
    size_t sz_dmode = al256(4);
    size_t sz_cnt   = al256((size_t)N * 4);
    size_t sz_off   = al256((size_t)(N + 1) * 4);
    size_t sz_ssrc  = al256((size_t)E * 4);
    size_t sz_hs    = al256((size_t)N * 128 * 2);
    size_t sz_hp    = al256((size_t)N * 64 * 2);
    size_t sz_eler  = al256((size_t)N * 2 * 4);
    size_t sz_stage = al256((size_t)N * 64 * 4);   // f32 stage
    size_t need = sz_dmode + 2 * sz_cnt + sz_off + sz_ssrc + sz_hs + sz_hp +
                  2 * sz_eler + sz_stage;
    int bad = (need > ws_size) ? 1 : 0;

    size_t cur = 0;
    auto alloc = [&](size_t bytes) {
        if (cur + bytes > ws_size) cur = 0;
        char* p = (char*)d_ws + cur;
        if (bytes <= ws_size) cur += bytes;
        return p;
    };
    int* dmode   = (int*)alloc(sz_dmode);
    int* cnt     = (int*)alloc(sz_cnt);
    int* cnt2    = (int*)alloc(sz_cnt);
    int* off     = (int*)alloc(sz_off);
    int* ssrc    = (int*)alloc(sz_ssrc);
    u16* hs      = (u16*)alloc(sz_hs);
    u16* hp      = (u16*)alloc(sz_hp);
    float* el    = (float*)alloc(sz_eler);
    float* er    = (float*)alloc(sz_eler);
    float* stage = (float*)alloc(sz_stage);

    float* H = (float*)d_out;  // transformed features [N,128] f32 live in d_out, dead at end

    hipMemsetAsync(cnt, 0, (size_t)N * 4, stream);
    hipMemsetAsync(cnt2, 0, (size_t)N * 4, stream);

    k_detect<<<1, 256, 0, stream>>>((const u16*)fvs, dmode);

    int eb = (E + 255) / 256;
    k_hist<<<eb, 256, 0, stream>>>(dst, cnt, E);
    k_scan<<<1, 1024, 0, stream>>>(cnt, off, N);
    k_fill<<<eb, 256, 0, stream>>>(src, dst, off, cnt2, ssrc, E);

    k_init<<<(N * 64 + 255) / 256, 256, 0, stream>>>(pos, hp, dmode, N * 64);

    int gb = (N + 63) / 64;
    int nb = (N + 3) / 4;

    // ---- layer 0 ----
    k_gemm<128, true><<<gb, 256, 0, stream>>>(fvs, hp, gW[0], grW[0], H, hs, N, 192, 128, dmode, 1);
    k_eler_gat<<<nb, 256, 0, stream>>>(H, gal[0], gar[0], el, er, dmode, N);
    k_edge_gat<<<nb, 256, 0, stream>>>(off, ssrc, H, el, er, hs, hs, nullptr, N, 0);
    k_gemm<64, false><<<gb, 256, 0, stream>>>(hp, nullptr, pW[0], nullptr, H, nullptr, N, 64, 64, dmode, 0);
    k_eler_pg<<<nb, 256, 0, stream>>>(H, pal[0], par[0], el, er, dmode, N);
    k_edge_pg<<<nb, 256, 0, stream>>>(off, ssrc, H, el, er, hp, N);

    // ---- layer 1 ----
    k_gemm<128, true><<<gb, 256, 0, stream>>>(hs, hp, gW[1], grW[1], H, hs, N, 192, 128, dmode, 0);
    k_eler_gat<<<nb, 256, 0, stream>>>(H, gal[1], gar[1], el, er, dmode, N);
    k_edge_gat<<<nb, 256, 0, stream>>>(off, ssrc, H, el, er, hs, hs, nullptr, N, 0);
    k_gemm<64, false><<<gb, 256, 0, stream>>>(hp, nullptr, pW[1], nullptr, H, nullptr, N, 64, 64, dmode, 0);
    k_eler_pg<<<nb, 256, 0, stream>>>(H, pal[1], par[1], el, er, dmode, N);
    k_edge_pg<<<nb, 256, 0, stream>>>(off, ssrc, H, el, er, hp, N);  // hp = pg1 out (tanh)

    // ---- output layer ----
    k_gemm<128, true><<<gb, 256, 0, stream>>>(hs, hp, gW[2], grW[2], H, hs, N, 192, 128, dmode, 0);
    k_eler_gat<<<nb, 256, 0, stream>>>(H, gal[2], gar[2], el, er, dmode, N);
    k_edge_gat<<<nb, 256, 0, stream>>>(off, ssrc, H, el, er, hs, nullptr, stage, N, 1);

    // H (= d_out) now dead; materialize outputs as f32.
    hipMemcpyAsync((float*)d_out, stage, (size_t)N * 64 * 4, hipMemcpyDeviceToDevice, stream);
    k_cvt<<<(N * 64 + 255) / 256, 256, 0, stream>>>(hp, (float*)d_out + (size_t)N * 64, N * 64);

    // Diagnostic: if workspace too small, out[0] reads ~100000 + MB*1000.
    if (bad) {
        float v = 100000.f + 1000.f * (float)(ws_size >> 20);
        k_tracer<<<1, 64, 0, stream>>>((float*)d_out, v);
    }
}

// Round 5
// 1086.848 us; speedup vs baseline: 1.0346x; 1.0346x over previous
//
#include <hip/hip_runtime.h>
#include <hip/hip_bf16.h>

#define NN 50000
#define NE 800000

typedef unsigned short u16;
typedef unsigned int u32;

__device__ __forceinline__ float bf2f(u16 u) {
    u32 x = ((u32)u) << 16;
    return __uint_as_float(x);
}
__device__ __forceinline__ u16 f2bf(float f) {
    u32 x = __float_as_uint(f);
    u32 r = (x + 0x7fffu + ((x >> 16) & 1u)) >> 16;  // round-nearest-even
    return (u16)r;
}
__device__ __forceinline__ u32 pack2(float a, float b) {
    return (u32)f2bf(a) | ((u32)f2bf(b) << 16);
}
__device__ __forceinline__ void unpack8(uint4 u, float* o) {
    o[0] = bf2f((u16)(u.x & 0xffff)); o[1] = bf2f((u16)(u.x >> 16));
    o[2] = bf2f((u16)(u.y & 0xffff)); o[3] = bf2f((u16)(u.y >> 16));
    o[4] = bf2f((u16)(u.z & 0xffff)); o[5] = bf2f((u16)(u.z >> 16));
    o[6] = bf2f((u16)(u.w & 0xffff)); o[7] = bf2f((u16)(u.w >> 16));
}
__device__ __forceinline__ float ldf(const void* p, size_t idx, int mode) {
    return mode ? bf2f(((const u16*)p)[idx]) : ((const float*)p)[idx];
}
__device__ __forceinline__ void ld8(const void* p, size_t idx, int mode, float* o) {
    if (mode) {
        uint4 u = *(const uint4*)((const u16*)p + idx);
        unpack8(u, o);
    } else {
        const float* f = (const float*)p + idx;
        float4 x = *(const float4*)f;
        float4 y = *(const float4*)(f + 4);
        o[0] = x.x; o[1] = x.y; o[2] = x.z; o[3] = x.w;
        o[4] = y.x; o[5] = y.y; o[6] = y.z; o[7] = y.w;
    }
}
__device__ __forceinline__ float lrelu(float x) { return x > 0.f ? x : 0.2f * x; }

// ---------------- diagnostics ----------------
__global__ void k_tracer(float* out, float v) {
    if (threadIdx.x == 0 && blockIdx.x == 0) out[0] = v;
}

// ---------------- dtype detect (0 = f32 inputs, 1 = bf16 inputs) ----------------
__global__ void k_detect(const u16* __restrict__ fvs, int* __restrict__ mode) {
    __shared__ int cnt[256];
    int t = threadIdx.x;
    int bad = 0;
    for (int i = 0; i < 16; i++) {
        u16 u = fvs[(size_t)(t * 16 + i) * 2];
        int e = (u >> 7) & 0xff;
        if (e == 255 || e >= 134 || e <= 100) bad++;
    }
    cnt[t] = bad;
    __syncthreads();
    for (int d = 128; d; d >>= 1) {
        if (t < d) cnt[t] += cnt[t + d];
        __syncthreads();
    }
    if (t == 0) *mode = (cnt[0] > 2048) ? 0 : 1;
}

// ---------------- CSR build ----------------
__global__ void k_hist(const int* __restrict__ dst, int* __restrict__ cnt, int E) {
    int e = blockIdx.x * blockDim.x + threadIdx.x;
    if (e < E) atomicAdd(&cnt[dst[e]], 1);
}

__global__ void k_scan(const int* __restrict__ cnt, int* __restrict__ off, int N) {
    __shared__ int sums[1024];
    int t = threadIdx.x;
    int chunk = (N + 1023) >> 10;
    int b = t * chunk;
    int s = 0;
    for (int i = 0; i < chunk; i++) { int idx = b + i; if (idx < N) s += cnt[idx]; }
    sums[t] = s;
    __syncthreads();
    for (int d = 1; d < 1024; d <<= 1) {
        int v = (t >= d) ? sums[t - d] : 0;
        __syncthreads();
        sums[t] += v;
        __syncthreads();
    }
    int run = (t == 0) ? 0 : sums[t - 1];
    for (int i = 0; i < chunk; i++) {
        int idx = b + i;
        if (idx < N) { off[idx] = run; run += cnt[idx]; }
    }
    if (t == 1023) off[N] = sums[1023];
}

__global__ void k_fill(const int* __restrict__ src, const int* __restrict__ dst,
                       const int* __restrict__ off, int* __restrict__ cnt2,
                       int* __restrict__ ssrc, int E) {
    int e = blockIdx.x * blockDim.x + threadIdx.x;
    if (e < E) {
        int d = dst[e];
        int p = off[d] + atomicAdd(&cnt2[d], 1);
        ssrc[p] = src[e];
    }
}

// ---------------- init: hp = bf16(pos) ----------------
__global__ void k_init(const void* __restrict__ pos, u16* __restrict__ hp,
                       const int* __restrict__ dmode, int n64) {
    int i = blockIdx.x * blockDim.x + threadIdx.x;
    if (i >= n64) return;
    int mode = *dmode;
    hp[i] = mode ? ((const u16*)pos)[i] : f2bf(((const float*)pos)[i]);
}

// ---------------- hp (bf16) -> f32 ----------------
__global__ void k_cvt(const u16* __restrict__ in, float* __restrict__ out, int n) {
    int i = blockIdx.x * blockDim.x + threadIdx.x;
    if (i < n) out[i] = bf2f(in[i]);
}

// ---------------- GEMM: C1[N,BM](f32), C2[N,BM](bf16) = [A1|A2][N,K] x B ----------------
// Conflict-free LDS: A stored transposed (b128 reads), B read as adjacent pairs
// strided by 32 (b64 reads). A1 and C2 may alias (in-place, own 64 rows only).
template <int BM, bool HASB2>
__launch_bounds__(256)
__global__ void k_gemm(const void* A1, const u16* __restrict__ A2,
                       const void* __restrict__ B1, const void* __restrict__ B2,
                       float* __restrict__ C1, u16* C2,
                       int N, int K, int s1, const int* __restrict__ dmode,
                       int a1_input) {
    constexpr int NG = BM / 32;  // col pair-groups per thread: 4 (BM=128) or 2
    __shared__ alignas(16) float As[32][68];   // [kk][row], pad 68 keeps b128 16B-aligned
    __shared__ alignas(16) float Bs1[32][BM];
    __shared__ alignas(16) float Bs2[HASB2 ? 32 : 1][HASB2 ? BM : 1];

    int mode = *dmode;
    int amode = a1_input ? mode : 1;
    int tid = threadIdx.x;
    int tx = tid & 15;        // column pair base = 2*tx
    int ty = tid >> 4;        // 0..15: rows ty*4 .. ty*4+3
    int r0 = blockIdx.x * 64;
    int arow = tid >> 2;      // staging row 0..63
    int acs = (tid & 3) * 8;  // staging col 0,8,16,24

    float acc1[4][2 * NG], acc2[4][2 * NG];
#pragma unroll
    for (int r = 0; r < 4; r++)
#pragma unroll
        for (int c = 0; c < 2 * NG; c++) { acc1[r][c] = 0.f; acc2[r][c] = 0.f; }

    for (int k0 = 0; k0 < K; k0 += 32) {
        // ---- stage A (transposed) ----
        {
            int gr = r0 + arow;
            float av[8];
#pragma unroll
            for (int i = 0; i < 8; i++) av[i] = 0.f;
            if (gr < N) {
                if (k0 >= 128) {
                    uint4 u = *(const uint4*)&A2[(size_t)gr * 64 + (k0 - 128) + acs];
                    unpack8(u, av);
                } else if (amode) {
                    uint4 u = *(const uint4*)((const u16*)A1 + (size_t)gr * s1 + k0 + acs);
                    unpack8(u, av);
                } else {
                    const float* Af = (const float*)A1 + (size_t)gr * s1 + k0 + acs;
                    float4 x = *(const float4*)Af;
                    float4 y = *(const float4*)(Af + 4);
                    av[0] = x.x; av[1] = x.y; av[2] = x.z; av[3] = x.w;
                    av[4] = y.x; av[5] = y.y; av[6] = y.z; av[7] = y.w;
                }
            }
#pragma unroll
            for (int i = 0; i < 8; i++) As[acs + i][arow] = av[i];
        }
        // ---- stage B ----
#pragma unroll
        for (int t = 0; t < BM / 64; t++) {
            int f8 = tid + t * 256;
            int row = f8 / (BM / 8);
            int col = (f8 - row * (BM / 8)) * 8;
            ld8(B1, (size_t)(k0 + row) * BM + col, mode, &Bs1[row][col]);
            if constexpr (HASB2) ld8(B2, (size_t)(k0 + row) * BM + col, mode, &Bs2[row][col]);
        }
        __syncthreads();
#pragma unroll
        for (int kk = 0; kk < 32; kk++) {
            float4 a4 = *(const float4*)&As[kk][ty * 4];  // one b128, conflict-free
            float a[4] = {a4.x, a4.y, a4.z, a4.w};
            float b1[2 * NG];
#pragma unroll
            for (int g = 0; g < NG; g++)
                *(float2*)&b1[2 * g] = *(const float2*)&Bs1[kk][2 * tx + 32 * g];
#pragma unroll
            for (int r = 0; r < 4; r++)
#pragma unroll
                for (int c = 0; c < 2 * NG; c++) acc1[r][c] = fmaf(a[r], b1[c], acc1[r][c]);
            if constexpr (HASB2) {
                float b2[2 * NG];
#pragma unroll
                for (int g = 0; g < NG; g++)
                    *(float2*)&b2[2 * g] = *(const float2*)&Bs2[kk][2 * tx + 32 * g];
#pragma unroll
                for (int r = 0; r < 4; r++)
#pragma unroll
                    for (int c = 0; c < 2 * NG; c++) acc2[r][c] = fmaf(a[r], b2[c], acc2[r][c]);
            }
        }
        __syncthreads();
    }
#pragma unroll
    for (int r = 0; r < 4; r++) {
        int gr = r0 + ty * 4 + r;
        if (gr >= N) continue;
#pragma unroll
        for (int g = 0; g < NG; g++) {
            *(float2*)&C1[(size_t)gr * BM + 2 * tx + 32 * g] =
                make_float2(acc1[r][2 * g], acc1[r][2 * g + 1]);
            if constexpr (HASB2) {
                *(u32*)&C2[(size_t)gr * BM + 2 * tx + 32 * g] =
                    pack2(acc2[r][2 * g], acc2[r][2 * g + 1]);
            }
        }
    }
}

// ---------------- attention record: att[n][8] = {el0,el1,er0,er1,m0,m1,d0,d1} ----------------
__global__ void k_eler_gat(const float* __restrict__ h, const void* __restrict__ al,
                           const void* __restrict__ ar, float* __restrict__ att,
                           const int* __restrict__ dmode, int N) {
    int node = blockIdx.x * (blockDim.x >> 6) + (threadIdx.x >> 6);
    int lane = threadIdx.x & 63;
    if (node >= N) return;
    int mode = *dmode;
    float h0 = h[(size_t)node * 128 + lane];
    float h1 = h[(size_t)node * 128 + 64 + lane];
    float e0 = h0 * ldf(al, lane, mode), e1 = h1 * ldf(al, 64 + lane, mode);
    float r0 = h0 * ldf(ar, lane, mode), r1 = h1 * ldf(ar, 64 + lane, mode);
#pragma unroll
    for (int o = 32; o; o >>= 1) {
        e0 += __shfl_xor(e0, o, 64); e1 += __shfl_xor(e1, o, 64);
        r0 += __shfl_xor(r0, o, 64); r1 += __shfl_xor(r1, o, 64);
    }
    if (lane == 0)
        *(float4*)&att[(size_t)node * 8] = make_float4(e0, e1, r0, r1);
}

__global__ void k_eler_pg(const float* __restrict__ h, const void* __restrict__ al,
                          const void* __restrict__ ar, float* __restrict__ att,
                          const int* __restrict__ dmode, int N) {
    int node = blockIdx.x * (blockDim.x >> 6) + (threadIdx.x >> 6);
    int lane = threadIdx.x & 63;
    if (node >= N) return;
    int mode = *dmode;
    float hv = h[(size_t)node * 64 + lane];
    float e = hv * ldf(al, lane, mode);
    float r = hv * ldf(ar, lane, mode);
#pragma unroll
    for (int o = 16; o; o >>= 1) {
        e += __shfl_xor(e, o, 64);
        r += __shfl_xor(r, o, 64);
    }
    if ((lane & 31) == 0) {
        int head = lane >> 5;
        att[(size_t)node * 8 + head] = e;
        att[(size_t)node * 8 + 2 + head] = r;
    }
}

// thread-per-dst: exact max + denom per head
__global__ void k_stats(const int* __restrict__ off, const int* __restrict__ ssrc,
                        float* __restrict__ att, int N) {
    int n = blockIdx.x * blockDim.x + threadIdx.x;
    if (n >= N) return;
    int beg = off[n], end = off[n + 1];
    float er0 = att[(size_t)n * 8 + 2], er1 = att[(size_t)n * 8 + 3];
    float m0 = -1e30f, m1 = -1e30f;
    for (int j = beg; j < end; j++) {
        int s = ssrc[j];
        float2 e = *(const float2*)&att[(size_t)s * 8];
        m0 = fmaxf(m0, lrelu(e.x + er0));
        m1 = fmaxf(m1, lrelu(e.y + er1));
    }
    float d0 = 0.f, d1 = 0.f;
    for (int j = beg; j < end; j++) {
        int s = ssrc[j];
        float2 e = *(const float2*)&att[(size_t)s * 8];
        d0 += __expf(lrelu(e.x + er0) - m0);
        d1 += __expf(lrelu(e.y + er1) - m1);
    }
    *(float4*)&att[(size_t)n * 8 + 4] = make_float4(m0, m1, d0, d1);
}

// ---------------- edge aggregation pass B (no cross-iteration dependency) ----------------
// res and outf may alias (same node row). For final_mean, outs = (float*)res (in-place,
// safe: all lanes' res reads precede the store instruction in the wave's program order).
__global__ void k_edge_gat(const int* __restrict__ off, const int* __restrict__ ssrc,
                           const float* __restrict__ h, const float* __restrict__ att,
                           const u16* res, u16* outf, float* outs,
                           int N, int final_mean) {
    int node = blockIdx.x * (blockDim.x >> 6) + (threadIdx.x >> 6);
    int lane = threadIdx.x & 63;
    if (node >= N) return;
    int beg = off[node], end = off[node + 1];
    float4 f4a = *(const float4*)&att[(size_t)node * 8];      // el0,el1,er0,er1
    float4 f4b = *(const float4*)&att[(size_t)node * 8 + 4];  // m0,m1,d0,d1
    float er0 = f4a.z, er1 = f4a.w, m0 = f4b.x, m1 = f4b.y;
    float O0 = 0.f, O1 = 0.f;
    int j = beg;
    for (; j + 1 < end; j += 2) {
        int sa = ssrc[j], sb = ssrc[j + 1];
        float2 ea = *(const float2*)&att[(size_t)sa * 8];
        float2 eb = *(const float2*)&att[(size_t)sb * 8];
        float ha0 = h[(size_t)sa * 128 + lane];
        float ha1 = h[(size_t)sa * 128 + 64 + lane];
        float hb0 = h[(size_t)sb * 128 + lane];
        float hb1 = h[(size_t)sb * 128 + 64 + lane];
        float ca0 = __expf(lrelu(ea.x + er0) - m0);
        float ca1 = __expf(lrelu(ea.y + er1) - m1);
        float cb0 = __expf(lrelu(eb.x + er0) - m0);
        float cb1 = __expf(lrelu(eb.y + er1) - m1);
        O0 += ca0 * ha0; O1 += ca1 * ha1;
        O0 += cb0 * hb0; O1 += cb1 * hb1;
    }
    if (j < end) {
        int s = ssrc[j];
        float2 e = *(const float2*)&att[(size_t)s * 8];
        float c0 = __expf(lrelu(e.x + er0) - m0);
        float c1 = __expf(lrelu(e.y + er1) - m1);
        O0 += c0 * h[(size_t)s * 128 + lane];
        O1 += c1 * h[(size_t)s * 128 + 64 + lane];
    }
    float o0 = (end > beg) ? O0 / f4b.z : 0.f;
    float o1 = (end > beg) ? O1 / f4b.w : 0.f;
    float a0 = o0 + bf2f(res[(size_t)node * 128 + lane]);
    float a1 = o1 + bf2f(res[(size_t)node * 128 + 64 + lane]);
    a0 = a0 > 0.f ? a0 : (__expf(a0) - 1.f);  // elu
    a1 = a1 > 0.f ? a1 : (__expf(a1) - 1.f);
    if (final_mean) {
        outs[(size_t)node * 64 + lane] = 0.5f * (a0 + a1);
    } else {
        outf[(size_t)node * 128 + lane] = f2bf(a0);
        outf[(size_t)node * 128 + 64 + lane] = f2bf(a1);
    }
}

__global__ void k_edge_pg(const int* __restrict__ off, const int* __restrict__ ssrc,
                          const float* __restrict__ h, const float* __restrict__ att,
                          u16* hp, int N) {
    int node = blockIdx.x * (blockDim.x >> 6) + (threadIdx.x >> 6);
    int lane = threadIdx.x & 63;
    if (node >= N) return;
    int head = lane >> 5;
    int beg = off[node], end = off[node + 1];
    float4 f4a = *(const float4*)&att[(size_t)node * 8];
    float4 f4b = *(const float4*)&att[(size_t)node * 8 + 4];
    float erh = head ? f4a.w : f4a.z;
    float mh = head ? f4b.y : f4b.x;
    float dh = head ? f4b.w : f4b.z;
    float O = 0.f;
    int j = beg;
    for (; j + 1 < end; j += 2) {
        int sa = ssrc[j], sb = ssrc[j + 1];
        float ela = att[(size_t)sa * 8 + head];
        float elb = att[(size_t)sb * 8 + head];
        float ha = h[(size_t)sa * 64 + lane];
        float hb = h[(size_t)sb * 64 + lane];
        O += __expf(lrelu(ela + erh) - mh) * ha;
        O += __expf(lrelu(elb + erh) - mh) * hb;
    }
    if (j < end) {
        int s = ssrc[j];
        float el = att[(size_t)s * 8 + head];
        O += __expf(lrelu(el + erh) - mh) * h[(size_t)s * 64 + lane];
    }
    float o = (end > beg) ? O / dh : 0.f;
    float a = tanhf(o + bf2f(hp[(size_t)node * 64 + lane]));
    hp[(size_t)node * 64 + lane] = f2bf(a);
}

// ---------------- launch ----------------
extern "C" void kernel_launch(void* const* d_in, const int* in_sizes, int n_in,
                              void* d_out, int out_size, void* d_ws, size_t ws_size,
                              hipStream_t stream) {
    const int N = NN, E = NE;
    const void* fvs = d_in[0];
    const void* pos = d_in[1];
    const int* src = (const int*)d_in[2];
    const int* dst = (const int*)d_in[3];
    const void* gW[3]  = {d_in[4],  d_in[8],  d_in[12]};
    const void* gal[3] = {d_in[5],  d_in[9],  d_in[13]};
    const void* gar[3] = {d_in[6],  d_in[10], d_in[14]};
    const void* grW[3] = {d_in[7],  d_in[11], d_in[15]};
    const void* pW[2]  = {d_in[16], d_in[19]};
    const void* pal[2] = {d_in[17], d_in[20]};
    const void* par[2] = {d_in[18], d_in[21]};

    // ---- workspace layout (wrap-safe) ----
    auto al256 = [](size_t b) { return (b + 255) & ~(size_t)255; };
    size_t sz_dmode = al256(4);
    size_t sz_att   = al256((size_t)N * 8 * 4);   // also hosts cnt/cnt2 during CSR build
    size_t sz_off   = al256((size_t)(N + 1) * 4);
    size_t sz_ssrc  = al256((size_t)E * 4);
    size_t sz_hs    = al256((size_t)N * 128 * 2);
    size_t sz_hp    = al256((size_t)N * 64 * 2);
    size_t need = sz_dmode + sz_att + sz_off + sz_ssrc + sz_hs + sz_hp;  // ~24.2 MB
    int bad = (need > ws_size) ? 1 : 0;

    size_t cur = 0;
    auto alloc = [&](size_t bytes) {
        if (cur + bytes > ws_size) cur = 0;
        char* p = (char*)d_ws + cur;
        if (bytes <= ws_size) cur += bytes;
        return p;
    };
    int* dmode  = (int*)alloc(sz_dmode);
    float* att  = (float*)alloc(sz_att);
    int* off    = (int*)alloc(sz_off);
    int* ssrc   = (int*)alloc(sz_ssrc);
    u16* hs     = (u16*)alloc(sz_hs);
    u16* hp     = (u16*)alloc(sz_hp);

    // cnt/cnt2 alias att (CSR build completes before att's first write)
    int* cnt  = (int*)att;
    int* cnt2 = (int*)((char*)att + al256((size_t)N * 4));

    float* H = (float*)d_out;  // transformed features [N,128] f32 in d_out, dead at end

    hipMemsetAsync(cnt, 0, (size_t)N * 4, stream);
    hipMemsetAsync(cnt2, 0, (size_t)N * 4, stream);

    k_detect<<<1, 256, 0, stream>>>((const u16*)fvs, dmode);

    int eb = (E + 255) / 256;
    k_hist<<<eb, 256, 0, stream>>>(dst, cnt, E);
    k_scan<<<1, 1024, 0, stream>>>(cnt, off, N);
    k_fill<<<eb, 256, 0, stream>>>(src, dst, off, cnt2, ssrc, E);

    k_init<<<(N * 64 + 255) / 256, 256, 0, stream>>>(pos, hp, dmode, N * 64);

    int gb = (N + 63) / 64;
    int nb = (N + 3) / 4;
    int sb = (N + 255) / 256;

    // ---- layer 0 ----
    k_gemm<128, true><<<gb, 256, 0, stream>>>(fvs, hp, gW[0], grW[0], H, hs, N, 192, 128, dmode, 1);
    k_eler_gat<<<nb, 256, 0, stream>>>(H, gal[0], gar[0], att, dmode, N);
    k_stats<<<sb, 256, 0, stream>>>(off, ssrc, att, N);
    k_edge_gat<<<nb, 256, 0, stream>>>(off, ssrc, H, att, hs, hs, nullptr, N, 0);
    k_gemm<64, false><<<gb, 256, 0, stream>>>(hp, nullptr, pW[0], nullptr, H, nullptr, N, 64, 64, dmode, 0);
    k_eler_pg<<<nb, 256, 0, stream>>>(H, pal[0], par[0], att, dmode, N);
    k_stats<<<sb, 256, 0, stream>>>(off, ssrc, att, N);
    k_edge_pg<<<nb, 256, 0, stream>>>(off, ssrc, H, att, hp, N);

    // ---- layer 1 ----
    k_gemm<128, true><<<gb, 256, 0, stream>>>(hs, hp, gW[1], grW[1], H, hs, N, 192, 128, dmode, 0);
    k_eler_gat<<<nb, 256, 0, stream>>>(H, gal[1], gar[1], att, dmode, N);
    k_stats<<<sb, 256, 0, stream>>>(off, ssrc, att, N);
    k_edge_gat<<<nb, 256, 0, stream>>>(off, ssrc, H, att, hs, hs, nullptr, N, 0);
    k_gemm<64, false><<<gb, 256, 0, stream>>>(hp, nullptr, pW[1], nullptr, H, nullptr, N, 64, 64, dmode, 0);
    k_eler_pg<<<nb, 256, 0, stream>>>(H, pal[1], par[1], att, dmode, N);
    k_stats<<<sb, 256, 0, stream>>>(off, ssrc, att, N);
    k_edge_pg<<<nb, 256, 0, stream>>>(off, ssrc, H, att, hp, N);  // hp = pg1 out (tanh)

    // ---- output layer ----
    k_gemm<128, true><<<gb, 256, 0, stream>>>(hs, hp, gW[2], grW[2], H, hs, N, 192, 128, dmode, 0);
    k_eler_gat<<<nb, 256, 0, stream>>>(H, gal[2], gar[2], att, dmode, N);
    k_stats<<<sb, 256, 0, stream>>>(off, ssrc, att, N);
    // final mean written in-place into hs rows as f32 (row = 256B = 64 floats)
    k_edge_gat<<<nb, 256, 0, stream>>>(off, ssrc, H, att, hs, nullptr, (float*)hs, N, 1);

    // H (= d_out) now dead; materialize outputs as f32.
    hipMemcpyAsync((float*)d_out, (float*)hs, (size_t)N * 64 * 4, hipMemcpyDeviceToDevice, stream);
    k_cvt<<<(N * 64 + 255) / 256, 256, 0, stream>>>(hp, (float*)d_out + (size_t)N * 64, N * 64);

    // Diagnostic: if workspace too small, out[0] reads ~100000 + MB*1000.
    if (bad) {
        float v = 100000.f + 1000.f * (float)(ws_size >> 20);
        k_tracer<<<1, 64, 0, stream>>>((float*)d_out, v);
    }
}

// Round 6
// 897.070 us; speedup vs baseline: 1.2535x; 1.2116x over previous
//
#include <hip/hip_runtime.h>
#include <hip/hip_bf16.h>

#define NN 50000
#define NE 800000

typedef unsigned short u16;
typedef unsigned int u32;

__device__ __forceinline__ float bf2f(u16 u) {
    u32 x = ((u32)u) << 16;
    return __uint_as_float(x);
}
__device__ __forceinline__ u16 f2bf(float f) {
    u32 x = __float_as_uint(f);
    u32 r = (x + 0x7fffu + ((x >> 16) & 1u)) >> 16;  // round-nearest-even
    return (u16)r;
}
__device__ __forceinline__ u32 pack2(float a, float b) {
    return (u32)f2bf(a) | ((u32)f2bf(b) << 16);
}
__device__ __forceinline__ void unpack8(uint4 u, float* o) {
    o[0] = bf2f((u16)(u.x & 0xffff)); o[1] = bf2f((u16)(u.x >> 16));
    o[2] = bf2f((u16)(u.y & 0xffff)); o[3] = bf2f((u16)(u.y >> 16));
    o[4] = bf2f((u16)(u.z & 0xffff)); o[5] = bf2f((u16)(u.z >> 16));
    o[6] = bf2f((u16)(u.w & 0xffff)); o[7] = bf2f((u16)(u.w >> 16));
}
__device__ __forceinline__ float ldf(const void* p, size_t idx, int mode) {
    return mode ? bf2f(((const u16*)p)[idx]) : ((const float*)p)[idx];
}
__device__ __forceinline__ float lrelu(float x) { return x > 0.f ? x : 0.2f * x; }

// ---------------- diagnostics ----------------
__global__ void k_tracer(float* out, float v) {
    if (threadIdx.x == 0 && blockIdx.x == 0) out[0] = v;
}

// ---------------- dtype detect (0 = f32 inputs, 1 = bf16 inputs) ----------------
__global__ void k_detect(const u16* __restrict__ fvs, int* __restrict__ mode) {
    __shared__ int cnt[256];
    int t = threadIdx.x;
    int bad = 0;
    for (int i = 0; i < 16; i++) {
        u16 u = fvs[(size_t)(t * 16 + i) * 2];
        int e = (u >> 7) & 0xff;
        if (e == 255 || e >= 134 || e <= 100) bad++;
    }
    cnt[t] = bad;
    __syncthreads();
    for (int d = 128; d; d >>= 1) {
        if (t < d) cnt[t] += cnt[t + d];
        __syncthreads();
    }
    if (t == 0) *mode = (cnt[0] > 2048) ? 0 : 1;
}

// ---------------- CSR build ----------------
__global__ void k_hist(const int* __restrict__ dst, int* __restrict__ cnt, int E) {
    int e = blockIdx.x * blockDim.x + threadIdx.x;
    if (e < E) atomicAdd(&cnt[dst[e]], 1);
}

__global__ void k_scan(const int* __restrict__ cnt, int* __restrict__ off, int N) {
    __shared__ int sums[1024];
    int t = threadIdx.x;
    int chunk = (N + 1023) >> 10;
    int b = t * chunk;
    int s = 0;
    for (int i = 0; i < chunk; i++) { int idx = b + i; if (idx < N) s += cnt[idx]; }
    sums[t] = s;
    __syncthreads();
    for (int d = 1; d < 1024; d <<= 1) {
        int v = (t >= d) ? sums[t - d] : 0;
        __syncthreads();
        sums[t] += v;
        __syncthreads();
    }
    int run = (t == 0) ? 0 : sums[t - 1];
    for (int i = 0; i < chunk; i++) {
        int idx = b + i;
        if (idx < N) { off[idx] = run; run += cnt[idx]; }
    }
    if (t == 1023) off[N] = sums[1023];
}

__global__ void k_fill(const int* __restrict__ src, const int* __restrict__ dst,
                       const int* __restrict__ off, int* __restrict__ cnt2,
                       int* __restrict__ ssrc, int E) {
    int e = blockIdx.x * blockDim.x + threadIdx.x;
    if (e < E) {
        int d = dst[e];
        int p = off[d] + atomicAdd(&cnt2[d], 1);
        ssrc[p] = src[e];
    }
}

// ---------------- init: hp = bf16(pos) ----------------
__global__ void k_init(const void* __restrict__ pos, u16* __restrict__ hp,
                       const int* __restrict__ dmode, int n64) {
    int i = blockIdx.x * blockDim.x + threadIdx.x;
    if (i >= n64) return;
    int mode = *dmode;
    hp[i] = mode ? ((const u16*)pos)[i] : f2bf(((const float*)pos)[i]);
}

// ---------------- hp (bf16) -> f32 ----------------
__global__ void k_cvt(const u16* __restrict__ in, float* __restrict__ out, int n) {
    int i = blockIdx.x * blockDim.x + threadIdx.x;
    if (i < n) out[i] = bf2f(in[i]);
}

// ---------------- GEMM + fused el/er epilogue ----------------
// C1[N,BM](f32), C2[N,BM](bf16) = [A1|A2][N,K] x B1/B2[K,BM]
// Software-pipelined: next K-tile's global loads issued during current FMAs.
// Epilogue computes att[n] = {el0,el1,er0,er1} from acc1 (16-lane shuffle tree).
// A1 and C2 may alias (in-place): all A reads precede the final barrier.
template <int BM, bool HASB2>
__launch_bounds__(256)
__global__ void k_gemm(const void* A1, const u16* __restrict__ A2,
                       const void* __restrict__ B1, const void* __restrict__ B2,
                       float* __restrict__ C1, u16* C2, float* __restrict__ att,
                       const void* __restrict__ al, const void* __restrict__ ar,
                       int N, int K, int s1, const int* __restrict__ dmode,
                       int a1_input) {
    constexpr int NG = BM / 32;   // col pair-groups per thread (4 or 2)
    constexpr int NT = BM / 64;   // B staging iters (2 or 1)
    __shared__ alignas(16) float As[32][68];
    __shared__ alignas(16) float Bs1[32][BM];
    __shared__ alignas(16) float Bs2[HASB2 ? 32 : 1][HASB2 ? BM : 1];

    int mode = *dmode;
    int amode = a1_input ? mode : 1;
    int tid = threadIdx.x;
    int tx = tid & 15, ty = tid >> 4;
    int r0 = blockIdx.x * 64;
    int arow = tid >> 2, acs = (tid & 3) * 8;
    int gr_a = r0 + arow;

    int brow[NT], bcol[NT];
#pragma unroll
    for (int t = 0; t < NT; t++) {
        int f8 = tid + t * 256;
        brow[t] = f8 / (BM / 8);
        bcol[t] = (f8 - brow[t] * (BM / 8)) * 8;
    }

    uint4 pa[2], pb1[2 * NT], pb2[2 * NT];

    auto loadA = [&](int k0) {
        if (gr_a >= N) return;
        if (k0 >= 128) {
            pa[0] = *(const uint4*)&A2[(size_t)gr_a * 64 + (k0 - 128) + acs];
        } else if (amode) {
            pa[0] = *(const uint4*)((const u16*)A1 + (size_t)gr_a * s1 + k0 + acs);
        } else {
            const float* f = (const float*)A1 + (size_t)gr_a * s1 + k0 + acs;
            pa[0] = *(const uint4*)f;
            pa[1] = *(const uint4*)(f + 4);
        }
    };
    auto loadB = [&](int k0) {
#pragma unroll
        for (int t = 0; t < NT; t++) {
            size_t idx = (size_t)(k0 + brow[t]) * BM + bcol[t];
            if (mode) {
                pb1[2 * t] = *(const uint4*)((const u16*)B1 + idx);
            } else {
                const float* f = (const float*)B1 + idx;
                pb1[2 * t] = *(const uint4*)f;
                pb1[2 * t + 1] = *(const uint4*)(f + 4);
            }
            if constexpr (HASB2) {
                if (mode) {
                    pb2[2 * t] = *(const uint4*)((const u16*)B2 + idx);
                } else {
                    const float* f = (const float*)B2 + idx;
                    pb2[2 * t] = *(const uint4*)f;
                    pb2[2 * t + 1] = *(const uint4*)(f + 4);
                }
            }
        }
    };
    auto stage = [&](int k0) {
        float av[8];
#pragma unroll
        for (int i = 0; i < 8; i++) av[i] = 0.f;
        if (gr_a < N) {
            if (k0 >= 128 || amode) unpack8(pa[0], av);
            else {
                const float* f = (const float*)pa;
#pragma unroll
                for (int i = 0; i < 8; i++) av[i] = f[i];
            }
        }
#pragma unroll
        for (int i = 0; i < 8; i++) As[acs + i][arow] = av[i];
#pragma unroll
        for (int t = 0; t < NT; t++) {
            float bv[8];
            if (mode) unpack8(pb1[2 * t], bv);
            else {
                const float* f = (const float*)&pb1[2 * t];
#pragma unroll
                for (int i = 0; i < 8; i++) bv[i] = f[i];
            }
            *(float4*)&Bs1[brow[t]][bcol[t]] = make_float4(bv[0], bv[1], bv[2], bv[3]);
            *(float4*)&Bs1[brow[t]][bcol[t] + 4] = make_float4(bv[4], bv[5], bv[6], bv[7]);
            if constexpr (HASB2) {
                if (mode) unpack8(pb2[2 * t], bv);
                else {
                    const float* f = (const float*)&pb2[2 * t];
#pragma unroll
                    for (int i = 0; i < 8; i++) bv[i] = f[i];
                }
                *(float4*)&Bs2[brow[t]][bcol[t]] = make_float4(bv[0], bv[1], bv[2], bv[3]);
                *(float4*)&Bs2[brow[t]][bcol[t] + 4] = make_float4(bv[4], bv[5], bv[6], bv[7]);
            }
        }
    };

    float acc1[4][2 * NG], acc2[4][2 * NG];
#pragma unroll
    for (int r = 0; r < 4; r++)
#pragma unroll
        for (int c = 0; c < 2 * NG; c++) { acc1[r][c] = 0.f; acc2[r][c] = 0.f; }

    loadA(0);
    loadB(0);
    for (int k0 = 0; k0 < K; k0 += 32) {
        stage(k0);
        __syncthreads();
        if (k0 + 32 < K) {    // prefetch next tile; latency hides under FMAs below
            loadA(k0 + 32);
            loadB(k0 + 32);
        }
#pragma unroll
        for (int kk = 0; kk < 32; kk++) {
            float4 a4 = *(const float4*)&As[kk][ty * 4];
            float a[4] = {a4.x, a4.y, a4.z, a4.w};
            float b1[2 * NG];
#pragma unroll
            for (int g = 0; g < NG; g++)
                *(float2*)&b1[2 * g] = *(const float2*)&Bs1[kk][2 * tx + 32 * g];
#pragma unroll
            for (int r = 0; r < 4; r++)
#pragma unroll
                for (int c = 0; c < 2 * NG; c++) acc1[r][c] = fmaf(a[r], b1[c], acc1[r][c]);
            if constexpr (HASB2) {
                float b2[2 * NG];
#pragma unroll
                for (int g = 0; g < NG; g++)
                    *(float2*)&b2[2 * g] = *(const float2*)&Bs2[kk][2 * tx + 32 * g];
#pragma unroll
                for (int r = 0; r < 4; r++)
#pragma unroll
                    for (int c = 0; c < 2 * NG; c++) acc2[r][c] = fmaf(a[r], b2[c], acc2[r][c]);
            }
        }
        __syncthreads();
    }

    // ---- epilogue: C stores + fused el/er ----
    float alv[2 * NG], arv[2 * NG];
#pragma unroll
    for (int g = 0; g < NG; g++)
#pragma unroll
        for (int u = 0; u < 2; u++) {
            int col = 2 * tx + 32 * g + u;
            alv[2 * g + u] = ldf(al, col, mode);
            arv[2 * g + u] = ldf(ar, col, mode);
        }
#pragma unroll
    for (int r = 0; r < 4; r++) {
        int gr = r0 + ty * 4 + r;
        float e0 = 0.f, e1 = 0.f, q0 = 0.f, q1 = 0.f;
#pragma unroll
        for (int g = 0; g < NG; g++)
#pragma unroll
            for (int u = 0; u < 2; u++) {
                float v = acc1[r][2 * g + u];
                if (g < NG / 2) { e0 += v * alv[2 * g + u]; q0 += v * arv[2 * g + u]; }
                else            { e1 += v * alv[2 * g + u]; q1 += v * arv[2 * g + u]; }
            }
#pragma unroll
        for (int o = 1; o <= 8; o <<= 1) {   // reduce across the 16 tx lanes
            e0 += __shfl_xor(e0, o, 64); e1 += __shfl_xor(e1, o, 64);
            q0 += __shfl_xor(q0, o, 64); q1 += __shfl_xor(q1, o, 64);
        }
        if (gr < N) {
#pragma unroll
            for (int g = 0; g < NG; g++) {
                *(float2*)&C1[(size_t)gr * BM + 2 * tx + 32 * g] =
                    make_float2(acc1[r][2 * g], acc1[r][2 * g + 1]);
                if constexpr (HASB2) {
                    *(u32*)&C2[(size_t)gr * BM + 2 * tx + 32 * g] =
                        pack2(acc2[r][2 * g], acc2[r][2 * g + 1]);
                }
            }
            if (tx == 0) *(float4*)&att[(size_t)gr * 4] = make_float4(e0, e1, q0, q1);
        }
    }
}

// ---------------- edge aggregation (self-contained softmax, wave per dst) ----------------
// Chunked-online exact softmax: phase1 lane=edge (max+denom+probs->LDS),
// phase2 lane=feature (O += p_j * h[s_j]). No __syncthreads (per-wave LDS only).
__global__ void k_edge_gat(const int* __restrict__ off, const int* __restrict__ ssrc,
                           const float* __restrict__ h, const float* __restrict__ att,
                           const u16* res, u16* outf, float* outs,
                           int N, int final_mean) {
    __shared__ float pbuf[4][2][64];
    __shared__ int sbuf[4][64];
    int wv = threadIdx.x >> 6;
    int node = blockIdx.x * 4 + wv;
    int lane = threadIdx.x & 63;
    if (node >= N) return;
    int beg = off[node], end = off[node + 1];
    float4 a4 = *(const float4*)&att[(size_t)node * 4];
    float er0 = a4.z, er1 = a4.w;
    float m0 = -1e30f, m1 = -1e30f, d0 = 0.f, d1 = 0.f, O0 = 0.f, O1 = 0.f;
    for (int c = beg; c < end; c += 64) {
        int cn = min(end - c, 64);
        int s = 0;
        float x0 = -1e30f, x1 = -1e30f;
        if (lane < cn) {
            s = ssrc[c + lane];
            float2 e = *(const float2*)&att[(size_t)s * 4];
            x0 = lrelu(e.x + er0);
            x1 = lrelu(e.y + er1);
        }
        float cm0 = x0, cm1 = x1;
#pragma unroll
        for (int o = 32; o; o >>= 1) {
            cm0 = fmaxf(cm0, __shfl_xor(cm0, o, 64));
            cm1 = fmaxf(cm1, __shfl_xor(cm1, o, 64));
        }
        float nm0 = fmaxf(m0, cm0), nm1 = fmaxf(m1, cm1);
        float p0 = (lane < cn) ? __expf(x0 - nm0) : 0.f;
        float p1 = (lane < cn) ? __expf(x1 - nm1) : 0.f;
        float cd0 = p0, cd1 = p1;
#pragma unroll
        for (int o = 32; o; o >>= 1) {
            cd0 += __shfl_xor(cd0, o, 64);
            cd1 += __shfl_xor(cd1, o, 64);
        }
        float sc0 = __expf(m0 - nm0), sc1 = __expf(m1 - nm1);
        d0 = d0 * sc0 + cd0; d1 = d1 * sc1 + cd1;
        O0 *= sc0; O1 *= sc1;
        m0 = nm0; m1 = nm1;
        pbuf[wv][0][lane] = p0;
        pbuf[wv][1][lane] = p1;
        sbuf[wv][lane] = s;
        int j = 0;
        for (; j + 1 < cn; j += 2) {
            int sa = sbuf[wv][j], sb = sbuf[wv][j + 1];
            float pa0 = pbuf[wv][0][j], pa1 = pbuf[wv][1][j];
            float pb0 = pbuf[wv][0][j + 1], pb1 = pbuf[wv][1][j + 1];
            float ha0 = h[(size_t)sa * 128 + lane];
            float ha1 = h[(size_t)sa * 128 + 64 + lane];
            float hb0 = h[(size_t)sb * 128 + lane];
            float hb1 = h[(size_t)sb * 128 + 64 + lane];
            O0 += pa0 * ha0 + pb0 * hb0;
            O1 += pa1 * ha1 + pb1 * hb1;
        }
        if (j < cn) {
            int sa = sbuf[wv][j];
            O0 += pbuf[wv][0][j] * h[(size_t)sa * 128 + lane];
            O1 += pbuf[wv][1][j] * h[(size_t)sa * 128 + 64 + lane];
        }
    }
    float o0 = (end > beg) ? O0 / d0 : 0.f;
    float o1 = (end > beg) ? O1 / d1 : 0.f;
    float a0 = o0 + bf2f(res[(size_t)node * 128 + lane]);
    float a1 = o1 + bf2f(res[(size_t)node * 128 + 64 + lane]);
    a0 = a0 > 0.f ? a0 : (__expf(a0) - 1.f);  // elu
    a1 = a1 > 0.f ? a1 : (__expf(a1) - 1.f);
    if (final_mean) {
        outs[(size_t)node * 64 + lane] = 0.5f * (a0 + a1);
    } else {
        outf[(size_t)node * 128 + lane] = f2bf(a0);
        outf[(size_t)node * 128 + 64 + lane] = f2bf(a1);
    }
}

__global__ void k_edge_pg(const int* __restrict__ off, const int* __restrict__ ssrc,
                          const float* __restrict__ h, const float* __restrict__ att,
                          u16* hp, int N) {
    __shared__ float pbuf[4][2][64];
    __shared__ int sbuf[4][64];
    int wv = threadIdx.x >> 6;
    int node = blockIdx.x * 4 + wv;
    int lane = threadIdx.x & 63;
    if (node >= N) return;
    int head = lane >> 5;
    int beg = off[node], end = off[node + 1];
    float4 a4 = *(const float4*)&att[(size_t)node * 4];
    float er0 = a4.z, er1 = a4.w;
    float m0 = -1e30f, m1 = -1e30f, d0 = 0.f, d1 = 0.f, O = 0.f;
    for (int c = beg; c < end; c += 64) {
        int cn = min(end - c, 64);
        int s = 0;
        float x0 = -1e30f, x1 = -1e30f;
        if (lane < cn) {
            s = ssrc[c + lane];
            float2 e = *(const float2*)&att[(size_t)s * 4];
            x0 = lrelu(e.x + er0);
            x1 = lrelu(e.y + er1);
        }
        float cm0 = x0, cm1 = x1;
#pragma unroll
        for (int o = 32; o; o >>= 1) {
            cm0 = fmaxf(cm0, __shfl_xor(cm0, o, 64));
            cm1 = fmaxf(cm1, __shfl_xor(cm1, o, 64));
        }
        float nm0 = fmaxf(m0, cm0), nm1 = fmaxf(m1, cm1);
        float p0 = (lane < cn) ? __expf(x0 - nm0) : 0.f;
        float p1 = (lane < cn) ? __expf(x1 - nm1) : 0.f;
        float cd0 = p0, cd1 = p1;
#pragma unroll
        for (int o = 32; o; o >>= 1) {
            cd0 += __shfl_xor(cd0, o, 64);
            cd1 += __shfl_xor(cd1, o, 64);
        }
        float sc0 = __expf(m0 - nm0), sc1 = __expf(m1 - nm1);
        d0 = d0 * sc0 + cd0; d1 = d1 * sc1 + cd1;
        O *= head ? sc1 : sc0;
        m0 = nm0; m1 = nm1;
        pbuf[wv][0][lane] = p0;
        pbuf[wv][1][lane] = p1;
        sbuf[wv][lane] = s;
        int j = 0;
        for (; j + 1 < cn; j += 2) {
            int sa = sbuf[wv][j], sb = sbuf[wv][j + 1];
            float pa = pbuf[wv][head][j], pb = pbuf[wv][head][j + 1];
            float ha = h[(size_t)sa * 64 + lane];
            float hb = h[(size_t)sb * 64 + lane];
            O += pa * ha + pb * hb;
        }
        if (j < cn) {
            int sa = sbuf[wv][j];
            O += pbuf[wv][head][j] * h[(size_t)sa * 64 + lane];
        }
    }
    float dh = head ? d1 : d0;
    float o = (end > beg) ? O / dh : 0.f;
    float a = tanhf(o + bf2f(hp[(size_t)node * 64 + lane]));
    hp[(size_t)node * 64 + lane] = f2bf(a);
}

// ---------------- launch ----------------
extern "C" void kernel_launch(void* const* d_in, const int* in_sizes, int n_in,
                              void* d_out, int out_size, void* d_ws, size_t ws_size,
                              hipStream_t stream) {
    const int N = NN, E = NE;
    const void* fvs = d_in[0];
    const void* pos = d_in[1];
    const int* src = (const int*)d_in[2];
    const int* dst = (const int*)d_in[3];
    const void* gW[3]  = {d_in[4],  d_in[8],  d_in[12]};
    const void* gal[3] = {d_in[5],  d_in[9],  d_in[13]};
    const void* gar[3] = {d_in[6],  d_in[10], d_in[14]};
    const void* grW[3] = {d_in[7],  d_in[11], d_in[15]};
    const void* pW[2]  = {d_in[16], d_in[19]};
    const void* pal[2] = {d_in[17], d_in[20]};
    const void* par[2] = {d_in[18], d_in[21]};

    // ---- workspace layout (wrap-safe) ----
    auto al256 = [](size_t b) { return (b + 255) & ~(size_t)255; };
    size_t sz_dmode = al256(4);
    size_t sz_att   = al256((size_t)N * 4 * 4);   // also hosts cnt/cnt2 during CSR build
    size_t sz_off   = al256((size_t)(N + 1) * 4);
    size_t sz_ssrc  = al256((size_t)E * 4);
    size_t sz_hs    = al256((size_t)N * 128 * 2);
    size_t sz_hp    = al256((size_t)N * 64 * 2);
    size_t need = sz_dmode + sz_att + sz_off + sz_ssrc + sz_hs + sz_hp;  // ~23 MB
    int bad = (need > ws_size) ? 1 : 0;

    size_t cur = 0;
    auto alloc = [&](size_t bytes) {
        if (cur + bytes > ws_size) cur = 0;
        char* p = (char*)d_ws + cur;
        if (bytes <= ws_size) cur += bytes;
        return p;
    };
    int* dmode  = (int*)alloc(sz_dmode);
    float* att  = (float*)alloc(sz_att);
    int* off    = (int*)alloc(sz_off);
    int* ssrc   = (int*)alloc(sz_ssrc);
    u16* hs     = (u16*)alloc(sz_hs);
    u16* hp     = (u16*)alloc(sz_hp);

    // cnt/cnt2 alias att (CSR build completes before att's first write; 800KB >= 400KB)
    int* cnt  = (int*)att;
    int* cnt2 = (int*)((char*)att + al256((size_t)N * 4));

    float* H = (float*)d_out;  // transformed features [N,128] f32 in d_out, dead at end

    hipMemsetAsync(cnt, 0, (size_t)N * 4, stream);
    hipMemsetAsync(cnt2, 0, (size_t)N * 4, stream);

    k_detect<<<1, 256, 0, stream>>>((const u16*)fvs, dmode);

    int eb = (E + 255) / 256;
    k_hist<<<eb, 256, 0, stream>>>(dst, cnt, E);
    k_scan<<<1, 1024, 0, stream>>>(cnt, off, N);
    k_fill<<<eb, 256, 0, stream>>>(src, dst, off, cnt2, ssrc, E);

    k_init<<<(N * 64 + 255) / 256, 256, 0, stream>>>(pos, hp, dmode, N * 64);

    int gb = (N + 63) / 64;
    int nb = (N + 3) / 4;

    // ---- layer 0 ----
    k_gemm<128, true><<<gb, 256, 0, stream>>>(fvs, hp, gW[0], grW[0], H, hs, att, gal[0], gar[0], N, 192, 128, dmode, 1);
    k_edge_gat<<<nb, 256, 0, stream>>>(off, ssrc, H, att, hs, hs, nullptr, N, 0);
    k_gemm<64, false><<<gb, 256, 0, stream>>>(hp, nullptr, pW[0], nullptr, H, nullptr, att, pal[0], par[0], N, 64, 64, dmode, 0);
    k_edge_pg<<<nb, 256, 0, stream>>>(off, ssrc, H, att, hp, N);

    // ---- layer 1 ----
    k_gemm<128, true><<<gb, 256, 0, stream>>>(hs, hp, gW[1], grW[1], H, hs, att, gal[1], gar[1], N, 192, 128, dmode, 0);
    k_edge_gat<<<nb, 256, 0, stream>>>(off, ssrc, H, att, hs, hs, nullptr, N, 0);
    k_gemm<64, false><<<gb, 256, 0, stream>>>(hp, nullptr, pW[1], nullptr, H, nullptr, att, pal[1], par[1], N, 64, 64, dmode, 0);
    k_edge_pg<<<nb, 256, 0, stream>>>(off, ssrc, H, att, hp, N);  // hp = pg1 out (tanh)

    // ---- output layer ----
    k_gemm<128, true><<<gb, 256, 0, stream>>>(hs, hp, gW[2], grW[2], H, hs, att, gal[2], gar[2], N, 192, 128, dmode, 0);
    // final mean written in-place into hs rows as f32 (row = 256B = 64 floats)
    k_edge_gat<<<nb, 256, 0, stream>>>(off, ssrc, H, att, hs, nullptr, (float*)hs, N, 1);

    // H (= d_out) now dead; materialize outputs as f32.
    hipMemcpyAsync((float*)d_out, (float*)hs, (size_t)N * 64 * 4, hipMemcpyDeviceToDevice, stream);
    k_cvt<<<(N * 64 + 255) / 256, 256, 0, stream>>>(hp, (float*)d_out + (size_t)N * 64, N * 64);

    // Diagnostic: if workspace too small, out[0] reads ~100000 + MB*1000.
    if (bad) {
        float v = 100000.f + 1000.f * (float)(ws_size >> 20);
        k_tracer<<<1, 64, 0, stream>>>((float*)d_out, v);
    }
}